// Round 17
// baseline (99.889 us; speedup 1.0000x reference)
//
#include <hip/hip_runtime.h>
#include <hip/hip_fp16.h>
#include <math.h>

typedef _Float16 f16x8 __attribute__((ext_vector_type(8)));
typedef _Float16 f16x4 __attribute__((ext_vector_type(4)));
typedef float f32x4 __attribute__((ext_vector_type(4)));

#define DD     128     // d
#define D2     256     // 2d
#define NB     8192    // batch
#define NCLS   5
#define KSPLIT 8
#define BM     128
#define PPAD   258     // row stride 516B = 129 dw == 1 mod 32 -> conflict-free
#define NSB    36      // 8x8 block-triangle: 28 off-diag (V+V^T) + 8 diag (raw V)
#define SB_BYTES  262144u              // 128 granules * 128 n * 16 B
#define TAIL_OFF  (36u * 262144u)      // W_w tail after all superblocks
#define PART_OFF  (10u * 1048576u)     // fp32 partials at +10 MB

// ---- prep: build symmetrized Vt fp16 in MFMA fragment layout ----------------------------
__global__ void prep_vt(const float* __restrict__ V, const float* __restrict__ Ww,
                        _Float16* __restrict__ Vt) {
    int t = blockIdx.x * 256 + threadIdx.x;      // thread per (granule-unit, n)
    int u = t >> 7;
    int n = t & 127;
    f16x8 v;
    if (u < NSB * 128) {
        int s = u >> 7, g = u & 127;
        int bi = 0, rem = s;
        while (rem >= 8 - bi) { rem -= 8 - bi; ++bi; }
        int bj = bi + rem;
        int i  = bi * 32 + (g >> 2);
        int j0 = bj * 32 + (g & 3) * 8;
        if (bi == bj) {
            #pragma unroll
            for (int e = 0; e < 8; ++e)
                v[e] = (_Float16)V[((size_t)i * 256 + j0 + e) * 128 + n];
        } else {
            #pragma unroll
            for (int e = 0; e < 8; ++e)
                v[e] = (_Float16)(V[((size_t)i * 256 + j0 + e) * 128 + n]
                                + V[((size_t)(j0 + e) * 256 + i) * 128 + n]);
        }
    } else {
        int g = u - NSB * 128;                   // 0..31
        int j0 = g * 8;
        #pragma unroll
        for (int e = 0; e < 8; ++e)
            v[e] = (_Float16)Ww[n * D2 + j0 + e];
    }
    *(f16x8*)(Vt + (size_t)u * 1024 + n * 8) = v;
}

// ---------------- main: tp_partial[ks][b][k] via outer-product-A MFMA GEMM ----------------
// 2x2 wave grid (mr=4, nr=4). PAIRED clusters: 8 loads -> one vmcnt(16) -> 32-MFMA burst
// under setprio(1). Halves wait/issue boundaries, doubles contiguous pipe occupancy.
__global__ __launch_bounds__(256, 2) void gemm_bilinear(
        const float* __restrict__ left, const float* __restrict__ right,
        const _Float16* __restrict__ Vt, float* __restrict__ part) {
    __shared__ _Float16 P[BM][PPAD];

    const int bid = blockIdx.x;
    const int ks  = bid & 7;       // == XCD id under round-robin dispatch -> slice per XCD L2
    const int m0  = (bid >> 3) * BM;
    const int tid = threadIdx.x;

    // stage phrase tile (fp32 global -> fp16 LDS), coalesced float4 reads
    for (int it = 0; it < 32; ++it) {
        int f4  = it * 256 + tid;          // float4 index over [128][256]
        int row = f4 >> 6;
        int col = (f4 & 63) * 4;
        const float* src = (col < DD) ? (left  + (size_t)(m0 + row) * DD + col)
                                      : (right + (size_t)(m0 + row) * DD + (col - DD));
        float4 x = *(const float4*)src;
        f16x4 hv;
        hv[0] = (_Float16)x.x; hv[1] = (_Float16)x.y;
        hv[2] = (_Float16)x.z; hv[3] = (_Float16)x.w;
        *(f16x4*)&P[row][col] = hv;
    }
    __syncthreads();

    const int lane = tid & 63;
    const int wid  = tid >> 6;
    const int wm   = wid >> 1, wn = wid & 1;   // 2x2 wave grid, 64x64 wave tile
    const int l15  = lane & 15, lg = lane >> 4;
    const int rowb = wm * 64;
    const int coln = wn * 64;

    f32x4 acc[4][4];
    #pragma unroll
    for (int u = 0; u < 4; ++u)
        #pragma unroll
        for (int w = 0; w < 4; ++w)
            acc[u][w] = (f32x4){0.f, 0.f, 0.f, 0.f};

    const unsigned lane_nbyte = (unsigned)((coln + l15) * 16);
    #define LDV(off) (*(const f16x8*)((const char*)Vt + (off)))

    // inline-asm B-load: 4 x dwordx4, saddr form + imm offsets. Pinned issue order.
    #define LOADB(BUF)                                                                    \
        asm volatile("global_load_dwordx4 %0, %4, %5\n\t"                                 \
                     "global_load_dwordx4 %1, %4, %5 offset:256\n\t"                      \
                     "global_load_dwordx4 %2, %4, %5 offset:512\n\t"                      \
                     "global_load_dwordx4 %3, %4, %5 offset:768"                          \
            : "=&v"(BUF[0]), "=&v"(BUF[1]), "=&v"(BUF[2]), "=&v"(BUF[3])                  \
            : "v"(voff), "s"(Vt));                                                        \
        voff += 8192u;

    // counted wait that DEFINES the two buffers it guards (dataflow-ordered)
    #define WAITN2(N, BA, BB)                                                             \
        asm volatile("s_waitcnt vmcnt(" #N ")"                                            \
            : "+v"(BA[0]), "+v"(BA[1]), "+v"(BA[2]), "+v"(BA[3]),                         \
              "+v"(BB[0]), "+v"(BB[1]), "+v"(BB[2]), "+v"(BB[3]));

    #define MFMA_CLUSTER(BUF, IBE)                                                        \
        _Pragma("unroll")                                                                 \
        for (int mr = 0; mr < 4; ++mr) {                                                  \
            const _Float16 sc = pis[mr][IBE];                                             \
            const f16x8 a = pj[mr] * sc;                                                  \
            _Pragma("unroll")                                                             \
            for (int nr = 0; nr < 4; ++nr)                                                \
                acc[mr][nr] = __builtin_amdgcn_mfma_f32_16x16x32_f16(a, BUF[nr], acc[mr][nr], 0, 0, 0); \
        }

    // paired 32-MFMA burst: one wait, one setprio window
    #define PAIR(N, BA, BB, IA, IB)                                                       \
        WAITN2(N, BA, BB)                                                                 \
        __builtin_amdgcn_s_setprio(1);                                                    \
        MFMA_CLUSTER(BA, IA)                                                              \
        MFMA_CLUSTER(BB, IB)                                                              \
        __builtin_amdgcn_s_setprio(0);

    #define LOAD_PIS(IBC)                                                                 \
        f16x8 pis[4];                                                                     \
        _Pragma("unroll")                                                                 \
        for (int mr = 0; mr < 4; ++mr)                                                    \
            pis[mr] = *(const f16x8*)&P[rowb + mr * 16 + l15][bi * 32 + (IBC) * 8];

    #pragma unroll 1
    for (int si = 0; si < 5; ++si) {
        int s, ibcS, ibcE;
        if (si < 4) { s = ks * 4 + si;      ibcS = 0;            ibcE = 4; }
        else        { s = 32 + (ks >> 1);   ibcS = (ks & 1) * 2; ibcE = ibcS + 2; }

        // decode (bi, bj) from triangle slot (wave-uniform scalar loop)
        int bi = 0, rem = s;
        while (rem >= 8 - bi) { rem -= 8 - bi; ++bi; }
        const int bj = bi + rem;

        // A j-fragments for this superblock (invariant over i)
        f16x8 pj[4];
        #pragma unroll
        for (int mr = 0; mr < 4; ++mr)
            pj[mr] = *(const f16x8*)&P[rowb + mr * 16 + l15][bj * 32 + lg * 8];

        unsigned voff = lane_nbyte + (unsigned)s * SB_BYTES + (unsigned)(lg * 2048)
                      + (unsigned)(ibcS * 65536);

        // prologue: fill 2 pairs (clusters 0..3 of this superblock)
        f16x8 B0[4], B1[4], B2[4], B3[4], B4[4], B5[4], B6[4], B7[4];
        LOADB(B0) LOADB(B1) LOADB(B2) LOADB(B3)

        // steady ibcs: pair p issues loads for pair p+2, waits vmcnt(16), bursts 32 MFMA
        #pragma unroll 1
        for (int ibc = ibcS; ibc < ibcE - 1; ++ibc) {
            LOAD_PIS(ibc)
            LOADB(B4) LOADB(B5)  PAIR(16, B0, B1, 0, 1)
            LOADB(B6) LOADB(B7)  PAIR(16, B2, B3, 2, 3)
            LOADB(B0) LOADB(B1)  PAIR(16, B4, B5, 4, 5)
            LOADB(B2) LOADB(B3)  PAIR(16, B6, B7, 6, 7)
        }

        // final ibc: pairs 0,1 issue the superblock's last clusters; pairs 2,3 drain
        // 8 -> 0. Every def consumed before register reuse (no R11 hazard).
        {
            LOAD_PIS(ibcE - 1)
            LOADB(B4) LOADB(B5)  PAIR(16, B0, B1, 0, 1)
            LOADB(B6) LOADB(B7)  PAIR(16, B2, B3, 2, 3)
                                 PAIR(8,  B4, B5, 4, 5)
                                 PAIR(0,  B6, B7, 6, 7)
        }
    }

    // last split also does the folded W_w matvec tail: A = P directly
    if (ks == KSPLIT - 1) {
        #pragma unroll 1
        for (int jc = 0; jc < 8; ++jc) {
            unsigned voff = TAIL_OFF + (unsigned)((jc * 4 + lg) * 2048) + lane_nbyte;
            f16x8 bfr[4];
            #pragma unroll
            for (int nr = 0; nr < 4; ++nr) bfr[nr] = LDV(voff + nr * 256);
            #pragma unroll
            for (int mr = 0; mr < 4; ++mr) {
                const f16x8 a = *(const f16x8*)&P[rowb + mr * 16 + l15][jc * 32 + lg * 8];
                #pragma unroll
                for (int nr = 0; nr < 4; ++nr)
                    acc[mr][nr] = __builtin_amdgcn_mfma_f32_16x16x32_f16(a, bfr[nr], acc[mr][nr], 0, 0, 0);
            }
        }
    }

    // write fp32 partials; C/D layout: col = lane&15, row = (lane>>4)*4 + q  [m89-verified]
    float* base = part + ((size_t)ks * NB + m0) * DD;
    #pragma unroll
    for (int mr = 0; mr < 4; ++mr)
        #pragma unroll
        for (int nr = 0; nr < 4; ++nr) {
            const int col = coln + nr * 16 + l15;
            #pragma unroll
            for (int q = 0; q < 4; ++q) {
                const int row = rowb + mr * 16 + lg * 4 + q;
                base[(size_t)row * DD + col] = acc[mr][nr][q];
            }
        }
}

// ---------------- epilogue: reduce splits, +W_b, tanh, 5-class logits, log_softmax --------
// 8 threads per batch row (k-split 16 each) + shuffle reduce
__global__ void finish(const float* __restrict__ part, const float* __restrict__ Wb,
                       const float* __restrict__ Wsw, const float* __restrict__ Wsb,
                       float* __restrict__ out) {
    int t  = blockIdx.x * 256 + threadIdx.x;
    int b  = t >> 3;
    int kq = t & 7;                 // k-eighth
    if (b >= NB) return;
    float lg[NCLS];
    #pragma unroll
    for (int c = 0; c < NCLS; ++c) lg[c] = 0.f;

    const float* pb = part + (size_t)b * DD + kq * 16;
    #pragma unroll 1
    for (int k4 = 0; k4 < 4; ++k4) {
        float4 tt = *(const float4*)(Wb + kq * 16 + k4 * 4);
        #pragma unroll
        for (int s = 0; s < KSPLIT; ++s) {
            float4 p = *(const float4*)(pb + (size_t)s * NB * DD + k4 * 4);
            tt.x += p.x; tt.y += p.y; tt.z += p.z; tt.w += p.w;
        }
        float tq[4] = {tt.x, tt.y, tt.z, tt.w};
        #pragma unroll
        for (int q = 0; q < 4; ++q) {
            float h = tanhf(tq[q]);
            int k = kq * 16 + k4 * 4 + q;
            #pragma unroll
            for (int c = 0; c < NCLS; ++c)
                lg[c] += h * Wsw[c * DD + k];
        }
    }
    // reduce across the 8 k-eighth lanes (lane bits 0..2)
    #pragma unroll
    for (int c = 0; c < NCLS; ++c) {
        lg[c] += __shfl_xor(lg[c], 1);
        lg[c] += __shfl_xor(lg[c], 2);
        lg[c] += __shfl_xor(lg[c], 4);
    }
    if (kq == 0) {
        #pragma unroll
        for (int c = 0; c < NCLS; ++c) lg[c] += Wsb[c];
        float mx = lg[0];
        #pragma unroll
        for (int c = 1; c < NCLS; ++c) mx = fmaxf(mx, lg[c]);
        float sum = 0.f;
        #pragma unroll
        for (int c = 0; c < NCLS; ++c) sum += expf(lg[c] - mx);
        float lse = logf(sum);
        #pragma unroll
        for (int c = 0; c < NCLS; ++c) out[b * NCLS + c] = lg[c] - mx - lse;
    }
}

extern "C" void kernel_launch(void* const* d_in, const int* in_sizes, int n_in,
                              void* d_out, int out_size, void* d_ws, size_t ws_size,
                              hipStream_t stream) {
    const float* left  = (const float*)d_in[0];
    const float* right = (const float*)d_in[1];
    const float* V     = (const float*)d_in[2];
    const float* Ww    = (const float*)d_in[3];
    const float* Wb    = (const float*)d_in[4];
    const float* Wsw   = (const float*)d_in[5];
    const float* Wsb   = (const float*)d_in[6];
    float* out = (float*)d_out;

    _Float16* Vt = (_Float16*)d_ws;                       // 9,502,720 B incl. tail
    float* part  = (float*)((char*)d_ws + PART_OFF);      // 33,554,432 B

    hipLaunchKernelGGL(prep_vt, dim3(2320), dim3(256), 0, stream, V, Ww, Vt);
    hipLaunchKernelGGL(gemm_bilinear, dim3((NB / BM) * KSPLIT), dim3(256), 0, stream,
                       left, right, Vt, part);
    hipLaunchKernelGGL(finish, dim3(NB * 8 / 256), dim3(256), 0, stream, part, Wb, Wsw, Wsb, out);
}

// Round 18
// 91.366 us; speedup vs baseline: 1.0933x; 1.0933x over previous
//
#include <hip/hip_runtime.h>
#include <hip/hip_fp16.h>
#include <math.h>

typedef _Float16 f16x8 __attribute__((ext_vector_type(8)));
typedef _Float16 f16x4 __attribute__((ext_vector_type(4)));
typedef float f32x4 __attribute__((ext_vector_type(4)));

#define DD     128     // d
#define D2     256     // 2d
#define NB     8192    // batch
#define NCLS   5
#define KSPLIT 8
#define BM     128
#define PPAD   258     // row stride 516B = 129 dw == 1 mod 32 -> conflict-free
#define NSB    36      // 8x8 block-triangle: 28 off-diag (V+V^T) + 8 diag (raw V)
#define SB_BYTES  262144u              // 128 granules * 128 n * 16 B
#define TAIL_OFF  (36u * 262144u)      // W_w tail after all superblocks
#define PART_OFF  (10u * 1048576u)     // fp16 partials at +10 MB (16.8 MB)

// ---- prep: build symmetrized Vt fp16 in MFMA fragment layout ----------------------------
__global__ void prep_vt(const float* __restrict__ V, const float* __restrict__ Ww,
                        _Float16* __restrict__ Vt) {
    int t = blockIdx.x * 256 + threadIdx.x;      // thread per (granule-unit, n)
    int u = t >> 7;
    int n = t & 127;
    f16x8 v;
    if (u < NSB * 128) {
        int s = u >> 7, g = u & 127;
        int bi = 0, rem = s;
        while (rem >= 8 - bi) { rem -= 8 - bi; ++bi; }
        int bj = bi + rem;
        int i  = bi * 32 + (g >> 2);
        int j0 = bj * 32 + (g & 3) * 8;
        if (bi == bj) {
            #pragma unroll
            for (int e = 0; e < 8; ++e)
                v[e] = (_Float16)V[((size_t)i * 256 + j0 + e) * 128 + n];
        } else {
            #pragma unroll
            for (int e = 0; e < 8; ++e)
                v[e] = (_Float16)(V[((size_t)i * 256 + j0 + e) * 128 + n]
                                + V[((size_t)(j0 + e) * 256 + i) * 128 + n]);
        }
    } else {
        int g = u - NSB * 128;                   // 0..31
        int j0 = g * 8;
        #pragma unroll
        for (int e = 0; e < 8; ++e)
            v[e] = (_Float16)Ww[n * D2 + j0 + e];
    }
    *(f16x8*)(Vt + (size_t)u * 1024 + n * 8) = v;
}

// ---------------- main: tp_partial[ks][b][k] via outer-product-A MFMA GEMM ----------------
// R14 structure (verified fastest): 2x2 wave grid (mr=4,nr=4), inline-asm B-loads,
// dataflow-carried counted vmcnt, depth-2, peeled final ibc. Changes vs R14:
// fp16 partial output (half C-write bytes) + W_w tail distributed (split ks does jc=ks).
__global__ __launch_bounds__(256, 2) void gemm_bilinear(
        const float* __restrict__ left, const float* __restrict__ right,
        const _Float16* __restrict__ Vt, _Float16* __restrict__ part) {
    __shared__ _Float16 P[BM][PPAD];

    const int bid = blockIdx.x;
    const int ks  = bid & 7;       // == XCD id under round-robin dispatch -> slice per XCD L2
    const int m0  = (bid >> 3) * BM;
    const int tid = threadIdx.x;

    // stage phrase tile (fp32 global -> fp16 LDS), coalesced float4 reads
    for (int it = 0; it < 32; ++it) {
        int f4  = it * 256 + tid;          // float4 index over [128][256]
        int row = f4 >> 6;
        int col = (f4 & 63) * 4;
        const float* src = (col < DD) ? (left  + (size_t)(m0 + row) * DD + col)
                                      : (right + (size_t)(m0 + row) * DD + (col - DD));
        float4 x = *(const float4*)src;
        f16x4 hv;
        hv[0] = (_Float16)x.x; hv[1] = (_Float16)x.y;
        hv[2] = (_Float16)x.z; hv[3] = (_Float16)x.w;
        *(f16x4*)&P[row][col] = hv;
    }
    __syncthreads();

    const int lane = tid & 63;
    const int wid  = tid >> 6;
    const int wm   = wid >> 1, wn = wid & 1;   // 2x2 wave grid, 64x64 wave tile
    const int l15  = lane & 15, lg = lane >> 4;
    const int rowb = wm * 64;
    const int coln = wn * 64;

    f32x4 acc[4][4];
    #pragma unroll
    for (int u = 0; u < 4; ++u)
        #pragma unroll
        for (int w = 0; w < 4; ++w)
            acc[u][w] = (f32x4){0.f, 0.f, 0.f, 0.f};

    const unsigned lane_nbyte = (unsigned)((coln + l15) * 16);
    #define LDV(off) (*(const f16x8*)((const char*)Vt + (off)))

    // inline-asm B-load: 4 x dwordx4, saddr form + imm offsets. Pinned issue order.
    #define LOADB(BUF)                                                                    \
        asm volatile("global_load_dwordx4 %0, %4, %5\n\t"                                 \
                     "global_load_dwordx4 %1, %4, %5 offset:256\n\t"                      \
                     "global_load_dwordx4 %2, %4, %5 offset:512\n\t"                      \
                     "global_load_dwordx4 %3, %4, %5 offset:768"                          \
            : "=&v"(BUF[0]), "=&v"(BUF[1]), "=&v"(BUF[2]), "=&v"(BUF[3])                  \
            : "v"(voff), "s"(Vt));                                                        \
        voff += 8192u;

    // counted wait that DEFINES the buffer it guards (dataflow-ordered, nothing else fenced)
    #define WAITN(N, BUF)                                                                 \
        asm volatile("s_waitcnt vmcnt(" #N ")"                                            \
            : "+v"(BUF[0]), "+v"(BUF[1]), "+v"(BUF[2]), "+v"(BUF[3]));

    #define MFMA_CLUSTER(BUF, IBE)                                                        \
        _Pragma("unroll")                                                                 \
        for (int mr = 0; mr < 4; ++mr) {                                                  \
            const _Float16 sc = pis[mr][IBE];                                             \
            const f16x8 a = pj[mr] * sc;                                                  \
            _Pragma("unroll")                                                             \
            for (int nr = 0; nr < 4; ++nr)                                                \
                acc[mr][nr] = __builtin_amdgcn_mfma_f32_16x16x32_f16(a, BUF[nr], acc[mr][nr], 0, 0, 0); \
        }

    #define LOAD_PIS(IBC)                                                                 \
        f16x8 pis[4];                                                                     \
        _Pragma("unroll")                                                                 \
        for (int mr = 0; mr < 4; ++mr)                                                    \
            pis[mr] = *(const f16x8*)&P[rowb + mr * 16 + l15][bi * 32 + (IBC) * 8];

    #pragma unroll 1
    for (int si = 0; si < 5; ++si) {
        int s, ibcS, ibcE;
        if (si < 4) { s = ks * 4 + si;      ibcS = 0;            ibcE = 4; }
        else        { s = 32 + (ks >> 1);   ibcS = (ks & 1) * 2; ibcE = ibcS + 2; }

        // decode (bi, bj) from triangle slot (wave-uniform scalar loop)
        int bi = 0, rem = s;
        while (rem >= 8 - bi) { rem -= 8 - bi; ++bi; }
        const int bj = bi + rem;

        // A j-fragments for this superblock (invariant over i)
        f16x8 pj[4];
        #pragma unroll
        for (int mr = 0; mr < 4; ++mr)
            pj[mr] = *(const f16x8*)&P[rowb + mr * 16 + l15][bj * 32 + lg * 8];

        unsigned voff = lane_nbyte + (unsigned)s * SB_BYTES + (unsigned)(lg * 2048)
                      + (unsigned)(ibcS * 65536);

        // prologue: fill pipeline to depth 2 (clusters 0,1). Nothing else in flight here.
        f16x8 B0[4], B1[4], B2[4], B3[4];
        LOADB(B0)
        LOADB(B1)

        // steady ibcs (all but the last of this superblock)
        #pragma unroll 1
        for (int ibc = ibcS; ibc < ibcE - 1; ++ibc) {
            LOAD_PIS(ibc)
            LOADB(B2)  WAITN(8, B0)  MFMA_CLUSTER(B0, 0)
            LOADB(B3)  WAITN(8, B1)  MFMA_CLUSTER(B1, 1)
            LOADB(B0)  WAITN(8, B2)  MFMA_CLUSTER(B2, 2)
            LOADB(B1)  WAITN(8, B3)  MFMA_CLUSTER(B3, 3)
            LOADB(B2)  WAITN(8, B0)  MFMA_CLUSTER(B0, 4)
            LOADB(B3)  WAITN(8, B1)  MFMA_CLUSTER(B1, 5)
            LOADB(B0)  WAITN(8, B2)  MFMA_CLUSTER(B2, 6)
            LOADB(B1)  WAITN(8, B3)  MFMA_CLUSTER(B3, 7)
        }

        // final ibc: steps 0-5 still prefetch in-superblock; 6,7 drain. Every def consumed.
        {
            LOAD_PIS(ibcE - 1)
            LOADB(B2)  WAITN(8, B0)  MFMA_CLUSTER(B0, 0)
            LOADB(B3)  WAITN(8, B1)  MFMA_CLUSTER(B1, 1)
            LOADB(B0)  WAITN(8, B2)  MFMA_CLUSTER(B2, 2)
            LOADB(B1)  WAITN(8, B3)  MFMA_CLUSTER(B3, 3)
            LOADB(B2)  WAITN(8, B0)  MFMA_CLUSTER(B0, 4)
            LOADB(B3)  WAITN(8, B1)  MFMA_CLUSTER(B1, 5)
                       WAITN(4, B2)  MFMA_CLUSTER(B2, 6)
                       WAITN(0, B3)  MFMA_CLUSTER(B3, 7)
        }
    }

    // W_w tail, DISTRIBUTED: split ks handles jc = ks only (balanced, no straggler)
    {
        const int jc = ks;
        unsigned voff = TAIL_OFF + (unsigned)((jc * 4 + lg) * 2048) + lane_nbyte;
        f16x8 bfr[4];
        #pragma unroll
        for (int nr = 0; nr < 4; ++nr) bfr[nr] = LDV(voff + nr * 256);
        #pragma unroll
        for (int mr = 0; mr < 4; ++mr) {
            const f16x8 a = *(const f16x8*)&P[rowb + mr * 16 + l15][jc * 32 + lg * 8];
            #pragma unroll
            for (int nr = 0; nr < 4; ++nr)
                acc[mr][nr] = __builtin_amdgcn_mfma_f32_16x16x32_f16(a, bfr[nr], acc[mr][nr], 0, 0, 0);
        }
    }

    // write fp16 partials; C/D layout: col = lane&15, row = (lane>>4)*4 + q  [m89-verified]
    _Float16* base = part + ((size_t)ks * NB + m0) * DD;
    #pragma unroll
    for (int mr = 0; mr < 4; ++mr)
        #pragma unroll
        for (int nr = 0; nr < 4; ++nr) {
            const int col = coln + nr * 16 + l15;
            #pragma unroll
            for (int q = 0; q < 4; ++q) {
                const int row = rowb + mr * 16 + lg * 4 + q;
                base[(size_t)row * DD + col] = (_Float16)acc[mr][nr][q];
            }
        }
}

// ---------------- epilogue: reduce fp16 splits, +W_b, tanh, logits, log_softmax ----------
// 8 threads per batch row (16 k each), f16x8 vector reads, shuffle reduce
__global__ void finish(const _Float16* __restrict__ part, const float* __restrict__ Wb,
                       const float* __restrict__ Wsw, const float* __restrict__ Wsb,
                       float* __restrict__ out) {
    int t  = blockIdx.x * 256 + threadIdx.x;
    int b  = t >> 3;
    int kq = t & 7;                 // k-sixteenth group of 16
    if (b >= NB) return;

    float sum[16];
    #pragma unroll
    for (int q = 0; q < 16; ++q) sum[q] = Wb[kq * 16 + q];

    const _Float16* pb = part + (size_t)b * DD + kq * 16;
    #pragma unroll
    for (int s = 0; s < KSPLIT; ++s) {
        const _Float16* ps = pb + (size_t)s * NB * DD;
        f16x8 v0 = *(const f16x8*)(ps);
        f16x8 v1 = *(const f16x8*)(ps + 8);
        #pragma unroll
        for (int e = 0; e < 8; ++e) { sum[e] += (float)v0[e]; sum[8 + e] += (float)v1[e]; }
    }

    float lg[NCLS];
    #pragma unroll
    for (int c = 0; c < NCLS; ++c) lg[c] = 0.f;
    #pragma unroll
    for (int q = 0; q < 16; ++q) {
        float h = tanhf(sum[q]);
        int k = kq * 16 + q;
        #pragma unroll
        for (int c = 0; c < NCLS; ++c)
            lg[c] += h * Wsw[c * DD + k];
    }
    // reduce across the 8 k-group lanes (lane bits 0..2)
    #pragma unroll
    for (int c = 0; c < NCLS; ++c) {
        lg[c] += __shfl_xor(lg[c], 1);
        lg[c] += __shfl_xor(lg[c], 2);
        lg[c] += __shfl_xor(lg[c], 4);
    }
    if (kq == 0) {
        #pragma unroll
        for (int c = 0; c < NCLS; ++c) lg[c] += Wsb[c];
        float mx = lg[0];
        #pragma unroll
        for (int c = 1; c < NCLS; ++c) mx = fmaxf(mx, lg[c]);
        float s = 0.f;
        #pragma unroll
        for (int c = 0; c < NCLS; ++c) s += expf(lg[c] - mx);
        float lse = logf(s);
        #pragma unroll
        for (int c = 0; c < NCLS; ++c) out[b * NCLS + c] = lg[c] - mx - lse;
    }
}

extern "C" void kernel_launch(void* const* d_in, const int* in_sizes, int n_in,
                              void* d_out, int out_size, void* d_ws, size_t ws_size,
                              hipStream_t stream) {
    const float* left  = (const float*)d_in[0];
    const float* right = (const float*)d_in[1];
    const float* V     = (const float*)d_in[2];
    const float* Ww    = (const float*)d_in[3];
    const float* Wb    = (const float*)d_in[4];
    const float* Wsw   = (const float*)d_in[5];
    const float* Wsb   = (const float*)d_in[6];
    float* out = (float*)d_out;

    _Float16* Vt   = (_Float16*)d_ws;                     // 9,502,720 B incl. tail
    _Float16* part = (_Float16*)((char*)d_ws + PART_OFF); // 16,777,216 B fp16 partials

    hipLaunchKernelGGL(prep_vt, dim3(2320), dim3(256), 0, stream, V, Ww, Vt);
    hipLaunchKernelGGL(gemm_bilinear, dim3((NB / BM) * KSPLIT), dim3(256), 0, stream,
                       left, right, Vt, part);
    hipLaunchKernelGGL(finish, dim3(NB * 8 / 256), dim3(256), 0, stream, part, Wb, Wsw, Wsb, out);
}